// Round 1
// baseline (98.731 us; speedup 1.0000x reference)
//
#include <hip/hip_runtime.h>

// PITLoss: dists[b,i,j] = mean_t (x[b,j,t] - y[b,i,t])^2 ; out = sum_b min over
// 24 permutations of sum_i dists[b,i,perm[i]].
// Memory-bound: 67.1 MB read once. Kernel 1 reduces over T into per-block
// partials (no atomics, no workspace memset needed since every slot is
// written). Kernel 2 (1 block) finishes the reduction + permutation min.

#define B_ 8
#define C_ 4
#define T_ 262144
#define CHUNKS 256     // blocks per batch; 256 blocks * 256 thr * 4 t = T_
#define THREADS 256

__global__ __launch_bounds__(THREADS) void pit_partial(
    const float* __restrict__ x, const float* __restrict__ y,
    float* __restrict__ partial)
{
    const int chunk = blockIdx.x;
    const int b = blockIdx.y;
    const int tid = threadIdx.x;
    // base offset for (b, c=0, t)
    const size_t base = (size_t)b * ((size_t)C_ * T_)
                      + (size_t)chunk * (THREADS * 4) + (size_t)tid * 4;

    float4 xv[C_], yv[C_];
#pragma unroll
    for (int c = 0; c < C_; ++c) {
        xv[c] = *(const float4*)(x + base + (size_t)c * T_);
        yv[c] = *(const float4*)(y + base + (size_t)c * T_);
    }

    // acc[i*4+j] = sum over this thread's 4 t of (x[b,j,t]-y[b,i,t])^2
    float acc[16];
#pragma unroll
    for (int i = 0; i < C_; ++i) {
#pragma unroll
        for (int j = 0; j < C_; ++j) {
            const float4 a = xv[j];
            const float4 d = yv[i];
            const float e0 = a.x - d.x;
            const float e1 = a.y - d.y;
            const float e2 = a.z - d.z;
            const float e3 = a.w - d.w;
            acc[i * 4 + j] = e0 * e0 + e1 * e1 + e2 * e2 + e3 * e3;
        }
    }

    // wave-64 butterfly reduce each of the 16 sums
#pragma unroll
    for (int p = 0; p < 16; ++p) {
        float v = acc[p];
#pragma unroll
        for (int off = 32; off >= 1; off >>= 1)
            v += __shfl_xor(v, off, 64);
        acc[p] = v;
    }

    __shared__ float red[4][16];
    const int lane = tid & 63;
    const int wave = tid >> 6;
    if (lane == 0) {
#pragma unroll
        for (int p = 0; p < 16; ++p) red[wave][p] = acc[p];
    }
    __syncthreads();
    if (tid < 16) {
        const float s = red[0][tid] + red[1][tid] + red[2][tid] + red[3][tid];
        // layout: partial[ij][b][chunk] -> contiguous over chunk for kernel 2
        partial[((size_t)tid * B_ + b) * CHUNKS + chunk] = s;
    }
}

__global__ __launch_bounds__(128) void pit_final(
    const float* __restrict__ partial, float* __restrict__ out)
{
    __shared__ float dists[B_][16];
    __shared__ float minb[B_];
    const int tid = threadIdx.x;   // 128 threads = 16 ij * 8 b

    {
        const int ij = tid >> 3;
        const int b  = tid & 7;
        const float4* src =
            (const float4*)(partial + ((size_t)ij * B_ + b) * CHUNKS);
        float s0 = 0.f, s1 = 0.f, s2 = 0.f, s3 = 0.f;
#pragma unroll 4
        for (int k = 0; k < CHUNKS / 4; k += 4) {
            const float4 v0 = src[k + 0];
            const float4 v1 = src[k + 1];
            const float4 v2 = src[k + 2];
            const float4 v3 = src[k + 3];
            s0 += v0.x + v0.y + v0.z + v0.w;
            s1 += v1.x + v1.y + v1.z + v1.w;
            s2 += v2.x + v2.y + v2.z + v2.w;
            s3 += v3.x + v3.y + v3.z + v3.w;
        }
        dists[b][ij] = (s0 + s1 + s2 + s3) * (1.0f / (float)T_);
    }
    __syncthreads();

    if (tid < B_) {
        static const int P[24][4] = {
            {0,1,2,3},{0,1,3,2},{0,2,1,3},{0,2,3,1},{0,3,1,2},{0,3,2,1},
            {1,0,2,3},{1,0,3,2},{1,2,0,3},{1,2,3,0},{1,3,0,2},{1,3,2,0},
            {2,0,1,3},{2,0,3,1},{2,1,0,3},{2,1,3,0},{2,3,0,1},{2,3,1,0},
            {3,0,1,2},{3,0,2,1},{3,1,0,2},{3,1,2,0},{3,2,0,1},{3,2,1,0}};
        const float* d = dists[tid];
        float best = 3.4e38f;
#pragma unroll
        for (int p = 0; p < 24; ++p) {
            const float c = d[0 + P[p][0]] + d[4 + P[p][1]]
                          + d[8 + P[p][2]] + d[12 + P[p][3]];
            best = fminf(best, c);
        }
        minb[tid] = best;
    }
    __syncthreads();

    if (tid == 0) {
        float s = 0.f;
#pragma unroll
        for (int b = 0; b < B_; ++b) s += minb[b];
        out[0] = s;
    }
}

extern "C" void kernel_launch(void* const* d_in, const int* in_sizes, int n_in,
                              void* d_out, int out_size, void* d_ws, size_t ws_size,
                              hipStream_t stream) {
    const float* x = (const float*)d_in[0];
    const float* y = (const float*)d_in[1];
    float* partial = (float*)d_ws;   // 16 * 8 * 256 floats = 128 KB

    dim3 grid(CHUNKS, B_);
    pit_partial<<<grid, THREADS, 0, stream>>>(x, y, partial);
    pit_final<<<1, 128, 0, stream>>>(partial, (float*)d_out);
}

// Round 2
// 94.987 us; speedup vs baseline: 1.0394x; 1.0394x over previous
//
#include <hip/hip_runtime.h>

// PITLoss: dists[b,i,j] = mean_t (x[b,j,t] - y[b,i,t])^2 ; out = sum_b min over
// 24 permutations of sum_i dists[b,i,perm[i]].
// Memory-bound: 67.1 MB read once -> ~11 us floor at 6.3 TB/s.
// R1 change: CHUNKS 256->64, 4 t-iterations per thread (512 B/thread) to
// amortize the wave butterfly reduction and raise per-thread load ILP.

#define B_ 8
#define C_ 4
#define T_ 262144
#define CHUNKS 64      // blocks per batch
#define THREADS 256
#define ITERS 4        // float4 iterations per thread: (T_/4)/(CHUNKS*THREADS)

__global__ __launch_bounds__(THREADS) void pit_partial(
    const float* __restrict__ x, const float* __restrict__ y,
    float* __restrict__ partial)
{
    const int chunk = blockIdx.x;
    const int b = blockIdx.y;
    const int tid = threadIdx.x;

    const float4* __restrict__ xb = (const float4*)(x + (size_t)b * C_ * T_);
    const float4* __restrict__ yb = (const float4*)(y + (size_t)b * C_ * T_);
    const int T4 = T_ / 4;

    float acc[16];
#pragma unroll
    for (int p = 0; p < 16; ++p) acc[p] = 0.f;

#pragma unroll
    for (int it = 0; it < ITERS; ++it) {
        const int idx = chunk * (THREADS * ITERS) + it * THREADS + tid;
        float4 xv[C_], yv[C_];
#pragma unroll
        for (int c = 0; c < C_; ++c) {
            xv[c] = xb[(size_t)c * T4 + idx];
            yv[c] = yb[(size_t)c * T4 + idx];
        }
#pragma unroll
        for (int i = 0; i < C_; ++i) {
#pragma unroll
            for (int j = 0; j < C_; ++j) {
                const float4 a = xv[j];
                const float4 d = yv[i];
                const float e0 = a.x - d.x;
                const float e1 = a.y - d.y;
                const float e2 = a.z - d.z;
                const float e3 = a.w - d.w;
                acc[i * 4 + j] += e0 * e0 + e1 * e1 + e2 * e2 + e3 * e3;
            }
        }
    }

    // wave-64 butterfly reduce each of the 16 sums (once per thread)
#pragma unroll
    for (int p = 0; p < 16; ++p) {
        float v = acc[p];
#pragma unroll
        for (int off = 32; off >= 1; off >>= 1)
            v += __shfl_xor(v, off, 64);
        acc[p] = v;
    }

    __shared__ float red[4][16];
    const int lane = tid & 63;
    const int wave = tid >> 6;
    if (lane == 0) {
#pragma unroll
        for (int p = 0; p < 16; ++p) red[wave][p] = acc[p];
    }
    __syncthreads();
    if (tid < 16) {
        const float s = red[0][tid] + red[1][tid] + red[2][tid] + red[3][tid];
        // layout: partial[ij][b][chunk] -> contiguous over chunk for kernel 2
        partial[((size_t)tid * B_ + b) * CHUNKS + chunk] = s;
    }
}

__global__ __launch_bounds__(128) void pit_final(
    const float* __restrict__ partial, float* __restrict__ out)
{
    __shared__ float dists[B_][16];
    __shared__ float minb[B_];
    const int tid = threadIdx.x;   // 128 threads = 16 ij * 8 b

    {
        const int ij = tid >> 3;
        const int b  = tid & 7;
        const float4* src =
            (const float4*)(partial + ((size_t)ij * B_ + b) * CHUNKS);
        float s = 0.f;
#pragma unroll
        for (int k = 0; k < CHUNKS / 4; ++k) {
            const float4 v = src[k];
            s += v.x + v.y + v.z + v.w;
        }
        dists[b][ij] = s * (1.0f / (float)T_);
    }
    __syncthreads();

    if (tid < B_) {
        static const int P[24][4] = {
            {0,1,2,3},{0,1,3,2},{0,2,1,3},{0,2,3,1},{0,3,1,2},{0,3,2,1},
            {1,0,2,3},{1,0,3,2},{1,2,0,3},{1,2,3,0},{1,3,0,2},{1,3,2,0},
            {2,0,1,3},{2,0,3,1},{2,1,0,3},{2,1,3,0},{2,3,0,1},{2,3,1,0},
            {3,0,1,2},{3,0,2,1},{3,1,0,2},{3,1,2,0},{3,2,0,1},{3,2,1,0}};
        const float* d = dists[tid];
        float best = 3.4e38f;
#pragma unroll
        for (int p = 0; p < 24; ++p) {
            const float c = d[0 + P[p][0]] + d[4 + P[p][1]]
                          + d[8 + P[p][2]] + d[12 + P[p][3]];
            best = fminf(best, c);
        }
        minb[tid] = best;
    }
    __syncthreads();

    if (tid == 0) {
        float s = 0.f;
#pragma unroll
        for (int b = 0; b < B_; ++b) s += minb[b];
        out[0] = s;
    }
}

extern "C" void kernel_launch(void* const* d_in, const int* in_sizes, int n_in,
                              void* d_out, int out_size, void* d_ws, size_t ws_size,
                              hipStream_t stream) {
    const float* x = (const float*)d_in[0];
    const float* y = (const float*)d_in[1];
    float* partial = (float*)d_ws;   // 16 * 8 * 64 floats = 32 KB

    dim3 grid(CHUNKS, B_);
    pit_partial<<<grid, THREADS, 0, stream>>>(x, y, partial);
    pit_final<<<1, 128, 0, stream>>>(partial, (float*)d_out);
}